// Round 6
// baseline (708.716 us; speedup 1.0000x reference)
//
#include <hip/hip_runtime.h>
#include <hip/hip_bf16.h>
#include <cstdint>

// N=1048576 nodes, B=32768 graphs, F=128, STEPS=6.
// The reference's setup overflows int32 (JAX no-x64): batch[i] =
// wrap_i32(i*32768) // 2^20 in {-2048..2047}. JAX segment ops DROP ids
// outside [0,B); gathers wrap but those contributions land in dropped ids.
// => active segments are 0..2047, each with exactly 8 chunks of 32 nodes;
// all other segments are empty -> [q_empty, 0]. Segment->chunk lists are
// built from d_in[1] on device (drop out-of-range), so we stay correct for
// both the overflowed and the clean (i//32) batch.
//
// Weight residency: 512 KB f32 == the ENTIRE per-CU register file, so full
// register residency is impossible (R5: spilled, scratch thrashed L2).
// Split: mp 0..3 (16 float4 = 64 VGPR) persistent in registers; mp 4..7
// streamed from L2 each step with ping-pong prefetch (<=8 float4 in flight).

#define NSTEPS   6
#define NSEG     32768
#define NCHUNK   32768      // 32-node chunks
#define MAXC     8          // exactly 8 chunks/active segment (structural)
#define XSTR     132        // padded LDS row stride (floats)
#define MTHREADS 1024
#define MGRID    256        // persistent: 1 WG/CU, each loops ~8 segments
#define ESHIFT   20.0f      // constant softmax shift (ratio-invariant)

__device__ __forceinline__ float sigmoidf_(float v) {
    return 1.0f / (1.0f + __expf(-v));
}

// ---------------- weight packing (merged W_ih + W_hh, h == q_star[:128]) ----
__global__ void pack_weights_kernel(const float* __restrict__ Wih,
                                    const float* __restrict__ Whh,
                                    const float* __restrict__ bih,
                                    const float* __restrict__ bhh,
                                    float* __restrict__ wtp,
                                    float* __restrict__ b4) {
    const int k = blockIdx.x;    // 0..255
    const int f = threadIdx.x;   // 0..127
    float w[4];
    #pragma unroll
    for (int j = 0; j < 4; ++j) {
        const int row = j * 128 + f;
        float v = Wih[row * 256 + k];
        if (k < 128) v += Whh[row * 128 + k];
        w[j] = v;
    }
    float4 wv; wv.x = w[0]; wv.y = w[1]; wv.z = w[2]; wv.w = w[3];
    reinterpret_cast<float4*>(wtp)[k * 128 + f] = wv;
    if (k == 0) {
        float4 bv;
        bv.x = bih[0 * 128 + f] + bhh[0 * 128 + f];
        bv.y = bih[1 * 128 + f] + bhh[1 * 128 + f];
        bv.z = bih[2 * 128 + f] + bhh[2 * 128 + f];
        bv.w = bih[3 * 128 + f] + bhh[3 * 128 + f];
        reinterpret_cast<float4*>(b4)[f] = bv;
    }
}

// ---------------- segment building ----------------
__global__ void zero_kernel(int* __restrict__ p, int n) {
    for (int i = blockIdx.x * blockDim.x + threadIdx.x; i < n;
         i += gridDim.x * blockDim.x) p[i] = 0;
}

__global__ void seg_count_kernel(const int* __restrict__ batch,
                                 int* __restrict__ counts) {
    const int c = blockIdx.x * blockDim.x + threadIdx.x;
    if (c < NCHUNK) {
        const int v = batch[c * 32];      // constant within a 32-node chunk
        if (v >= 0 && v < NSEG)           // JAX segment ops DROP out-of-range
            atomicAdd(&counts[v], 1);
    }
}

__global__ __launch_bounds__(1024)
void scan_kernel(const int* __restrict__ counts,
                 int* __restrict__ offs, int* __restrict__ cursor,
                 int* __restrict__ activeList, int* __restrict__ nActive) {
    __shared__ int sc[1024];
    const int t = threadIdx.x;
    const int base = t * 32;
    int local[32];
    int sum = 0;
    #pragma unroll
    for (int j = 0; j < 32; ++j) { local[j] = counts[base + j]; sum += local[j]; }
    sc[t] = sum;
    __syncthreads();
    for (int d = 1; d < 1024; d <<= 1) {
        const int v = (t >= d) ? sc[t - d] : 0;
        __syncthreads();
        sc[t] += v;
        __syncthreads();
    }
    int run = sc[t] - sum;   // exclusive prefix
    for (int j = 0; j < 32; ++j) {
        const int s = base + j;
        offs[s] = run;
        cursor[s] = run;
        if (local[j] > 0) {
            const int idx = atomicAdd(nActive, 1);
            activeList[idx] = s;
        }
        run += local[j];
    }
}

__global__ void fill_kernel(const int* __restrict__ batch,
                            int* __restrict__ cursor,
                            int* __restrict__ chunk_list) {
    const int c = blockIdx.x * blockDim.x + threadIdx.x;
    if (c < NCHUNK) {
        const int v = batch[c * 32];
        if (v >= 0 && v < NSEG) {
            const int pos = atomicAdd(&cursor[v], 1);
            chunk_list[pos] = c;
        }
    }
}

// ---------------- shared trajectory for empty graphs (r == 0) --------------
__global__ __launch_bounds__(128)
void empty_traj_kernel(const float* __restrict__ wtp,
                       const float* __restrict__ b4,
                       float* __restrict__ qe) {
    __shared__ float q_s[128];
    const int f = threadIdx.x;
    const float4 bb = reinterpret_cast<const float4*>(b4)[f];
    q_s[f] = 0.0f;
    float c = 0.0f;
    __syncthreads();
    for (int step = 0; step < NSTEPS; ++step) {
        float a0 = 0.f, a1 = 0.f, a2 = 0.f, a3 = 0.f;
        for (int k = 0; k < 128; ++k) {        // r part is zero: only k<128
            const float4 w = reinterpret_cast<const float4*>(wtp)[k * 128 + f];
            const float qv = q_s[k];
            a0 = fmaf(w.x, qv, a0); a1 = fmaf(w.y, qv, a1);
            a2 = fmaf(w.z, qv, a2); a3 = fmaf(w.w, qv, a3);
        }
        __syncthreads();
        c = sigmoidf_(a1 + bb.y) * c + sigmoidf_(a0 + bb.x) * tanhf(a2 + bb.z);
        q_s[f] = sigmoidf_(a3 + bb.w) * tanhf(c);
        __syncthreads();
    }
    qe[f] = q_s[f];
}

__global__ void bcast_empty_kernel(const int* __restrict__ counts,
                                   const float* __restrict__ qe,
                                   float* __restrict__ out) {
    const int lane = threadIdx.x & 63;
    const int wave0 = (blockIdx.x * blockDim.x + threadIdx.x) >> 6;
    const int nwave = (gridDim.x * blockDim.x) >> 6;
    float4 v = make_float4(0.f, 0.f, 0.f, 0.f);
    if (lane < 32) v = reinterpret_cast<const float4*>(qe)[lane];
    for (int s = wave0; s < NSEG; s += nwave) {
        if (counts[s] != 0) continue;
        reinterpret_cast<float4*>(out)[(size_t)s * 64 + lane] = v;
    }
}

// ---------------- main: persistent WGs, half-resident weights --------------
// 1024 threads = 16 waves. Thread (f = t>>3, ko = t&7) owns gate column f,
// k-slice {mp*32 + ko*4 .. +3}. mp 0..3 weights live in registers (64 VGPR,
// fits the 128/wave budget at 16 waves/CU); mp 4..7 stream from L2 per step
// with ping-pong prefetch. 4 barriers/step via double-buffered q_star.
__global__ __launch_bounds__(MTHREADS, 1)
void main_seg_kernel(const float* __restrict__ x,
                     const float* __restrict__ wtp,
                     const float* __restrict__ b4,
                     const int* __restrict__ counts,
                     const int* __restrict__ offs,
                     const int* __restrict__ chunk_list,
                     const int* __restrict__ activeList,
                     const int* __restrict__ nActive,
                     float* __restrict__ out) {
    __shared__ __align__(16) float x_s[MAXC * 32 * XSTR];   // 135168 B
    __shared__ __align__(16) float q_s[2][256];             // dbuf [q | r]
    __shared__ __align__(16) float e_s[256];                // exp(e - 20)
    __shared__ float rpart_s[1024];                         // 8 x 128
    __shared__ float dsum_s[16];
    __shared__ int   clist_s[MAXC];
    __shared__ int   cnt_s;

    const int t  = threadIdx.x;
    const int ko = t & 7;                 // k-eighth
    const int f  = t >> 3;                // 0..127
    const float4 bb = reinterpret_cast<const float4*>(b4)[f];
    const int nAct = *nActive;
    const float4* wtp4 = reinterpret_cast<const float4*>(wtp);

    // ---- persistent register half: mp 0..3 -> 16 float4 = 64 VGPR ----
    float4 wreg[4][4];
    #pragma unroll
    for (int mp = 0; mp < 4; ++mp)
        #pragma unroll
        for (int j4 = 0; j4 < 4; ++j4)
            wreg[mp][j4] = wtp4[(mp * 32 + ko * 4 + j4) * 128 + f];

    for (int w = blockIdx.x; w < nAct; w += gridDim.x) {
        const int s = activeList[w];
        if (t == 0) {
            int cnt = counts[s];
            if (cnt > MAXC) cnt = MAXC;    // structurally impossible; clamp
            const int off = offs[s];
            for (int j = 0; j < cnt; ++j) clist_s[j] = chunk_list[off + j];
            for (int a = 1; a < cnt; ++a) {          // sort: deterministic
                const int key = clist_s[a];
                int b = a - 1;
                while (b >= 0 && clist_s[b] > key) { clist_s[b+1] = clist_s[b]; --b; }
                clist_s[b+1] = key;
            }
            cnt_s = cnt;
        }
        if (t < 256) q_s[0][t] = 0.0f;
        __syncthreads();
        const int cnt = cnt_s;
        const int nv  = cnt * 32;          // valid nodes (256 in practice)

        // ---- stage chunks into LDS (f32, padded rows), coalesced float4 ----
        for (int p = t; p < cnt * 1024; p += MTHREADS) {
            const int j   = p >> 10;
            const int q4  = p & 1023;
            const int row = q4 >> 5;
            const int c4  = q4 & 31;
            const float4 v = reinterpret_cast<const float4*>(x)
                                [(size_t)clist_s[j] * 1024 + q4];
            *reinterpret_cast<float4*>(&x_s[(j * 32 + row) * XSTR + c4 * 4]) = v;
        }
        float c_reg = 0.0f;
        __syncthreads();

        for (int step = 0; step < NSTEPS; ++step) {
            const float* qin  = q_s[step & 1];
            float*       qout = q_s[(step & 1) ^ 1];

            float a0 = 0.f, a1 = 0.f, a2 = 0.f, a3 = 0.f;

            // prefetch streamed group mp=4 BEFORE the register-half FMAs
            float4 wn0 = wtp4[(4 * 32 + ko * 4 + 0) * 128 + f];
            float4 wn1 = wtp4[(4 * 32 + ko * 4 + 1) * 128 + f];
            float4 wn2 = wtp4[(4 * 32 + ko * 4 + 2) * 128 + f];
            float4 wn3 = wtp4[(4 * 32 + ko * 4 + 3) * 128 + f];

            // ---- register half: mp 0..3 ----
            #pragma unroll
            for (int mp = 0; mp < 4; ++mp) {
                const float4 qv =
                    *reinterpret_cast<const float4*>(&qin[mp * 32 + ko * 4]);
                #pragma unroll
                for (int j4 = 0; j4 < 4; ++j4) {
                    const float4 wv = wreg[mp][j4];
                    const float qj = (j4 == 0) ? qv.x : (j4 == 1) ? qv.y
                                   : (j4 == 2) ? qv.z : qv.w;
                    a0 = fmaf(wv.x, qj, a0); a1 = fmaf(wv.y, qj, a1);
                    a2 = fmaf(wv.z, qj, a2); a3 = fmaf(wv.w, qj, a3);
                }
            }

            // ---- streamed half: mp 4..7, ping-pong prefetch ----
            #pragma unroll
            for (int mp = 4; mp < 8; ++mp) {
                const float4 wc0 = wn0, wc1 = wn1, wc2 = wn2, wc3 = wn3;
                if (mp < 7) {
                    wn0 = wtp4[((mp + 1) * 32 + ko * 4 + 0) * 128 + f];
                    wn1 = wtp4[((mp + 1) * 32 + ko * 4 + 1) * 128 + f];
                    wn2 = wtp4[((mp + 1) * 32 + ko * 4 + 2) * 128 + f];
                    wn3 = wtp4[((mp + 1) * 32 + ko * 4 + 3) * 128 + f];
                }
                const float4 qv =
                    *reinterpret_cast<const float4*>(&qin[mp * 32 + ko * 4]);
                a0 = fmaf(wc0.x, qv.x, a0); a1 = fmaf(wc0.y, qv.x, a1);
                a2 = fmaf(wc0.z, qv.x, a2); a3 = fmaf(wc0.w, qv.x, a3);
                a0 = fmaf(wc1.x, qv.y, a0); a1 = fmaf(wc1.y, qv.y, a1);
                a2 = fmaf(wc1.z, qv.y, a2); a3 = fmaf(wc1.w, qv.y, a3);
                a0 = fmaf(wc2.x, qv.z, a0); a1 = fmaf(wc2.y, qv.z, a1);
                a2 = fmaf(wc2.z, qv.z, a2); a3 = fmaf(wc2.w, qv.z, a3);
                a0 = fmaf(wc3.x, qv.w, a0); a1 = fmaf(wc3.y, qv.w, a1);
                a2 = fmaf(wc3.z, qv.w, a2); a3 = fmaf(wc3.w, qv.w, a3);
            }

            a0 += __shfl_xor(a0, 1); a0 += __shfl_xor(a0, 2); a0 += __shfl_xor(a0, 4);
            a1 += __shfl_xor(a1, 1); a1 += __shfl_xor(a1, 2); a1 += __shfl_xor(a1, 4);
            a2 += __shfl_xor(a2, 1); a2 += __shfl_xor(a2, 2); a2 += __shfl_xor(a2, 4);
            a3 += __shfl_xor(a3, 1); a3 += __shfl_xor(a3, 2); a3 += __shfl_xor(a3, 4);
            if (ko == 0) {                 // 128 owner lanes: LSTM pointwise
                const float gi = a0 + bb.x, gf = a1 + bb.y;
                const float gg = a2 + bb.z, go = a3 + bb.w;
                c_reg = sigmoidf_(gf) * c_reg + sigmoidf_(gi) * tanhf(gg);
                qout[f] = sigmoidf_(go) * tanhf(c_reg);   // no WAR: other buffer
            }
            __syncthreads();               // B2: new q visible

            // ---- attention: 4 lanes per node; p = exp(x_n.q - 20) ----
            {
                const int n  = t >> 2;     // 0..255
                const int kh = t & 3;
                const float* xr = &x_s[n * XSTR + kh * 32];
                const float* qr = &qout[kh * 32];
                float part = 0.f;
                #pragma unroll
                for (int kk = 0; kk < 32; kk += 4) {
                    const float4 xv = *reinterpret_cast<const float4*>(xr + kk);
                    const float4 qv = *reinterpret_cast<const float4*>(qr + kk);
                    part = fmaf(xv.x, qv.x, part);
                    part = fmaf(xv.y, qv.y, part);
                    part = fmaf(xv.z, qv.z, part);
                    part = fmaf(xv.w, qv.w, part);
                }
                part += __shfl_xor(part, 1);
                part += __shfl_xor(part, 2);             // full 128-dot
                const float p = (n < nv) ? __expf(part - ESHIFT) : 0.f;
                if (kh == 0) e_s[n] = p;
                float ws = (kh == 0) ? p : 0.f;          // wave denom partial
                ws += __shfl_xor(ws, 4);  ws += __shfl_xor(ws, 8);
                ws += __shfl_xor(ws, 16); ws += __shfl_xor(ws, 32);
                if ((t & 63) == 0) dsum_s[t >> 6] = ws;
            }
            __syncthreads();               // B3: e_s + dsum visible

            // ---- readout partials: wave nh owns 32-node chunk ----
            {
                const int nh  = t >> 7;    // 0..7
                const int fr  = t & 127;
                const int nlo = nh * 32;
                float part = 0.f;
                if (nlo < nv) {
                    const float* xc = &x_s[nlo * XSTR + fr];
                    const float* ec = &e_s[nlo];
                    #pragma unroll 8
                    for (int j = 0; j < 32; ++j)
                        part = fmaf(ec[j], xc[j * XSTR], part);
                }
                rpart_s[nh * 128 + fr] = part;
            }
            __syncthreads();               // B4: rpart visible
            if (t < 128) {
                float den = 0.f;
                #pragma unroll
                for (int j = 0; j < 16; ++j) den += dsum_s[j];
                const float rsum = rpart_s[t]       + rpart_s[128 + t]
                                 + rpart_s[256 + t] + rpart_s[384 + t]
                                 + rpart_s[512 + t] + rpart_s[640 + t]
                                 + rpart_s[768 + t] + rpart_s[896 + t];
                qout[128 + t] = rsum / den;
            }
            __syncthreads();               // B5: r visible for next gate phase
        }
        // after 6 steps the final q_star sits in q_s[0]
        if (t < 64)
            reinterpret_cast<float4*>(out + (size_t)s * 256)[t] =
                reinterpret_cast<const float4*>(&q_s[0][0])[t];
        __syncthreads();                   // before LDS reuse for next segment
    }
}

extern "C" void kernel_launch(void* const* d_in, const int* in_sizes, int n_in,
                              void* d_out, int out_size, void* d_ws, size_t ws_size,
                              hipStream_t stream) {
    (void)in_sizes; (void)n_in; (void)out_size; (void)ws_size;
    const float* x    = (const float*)d_in[0];
    const int*   batch = (const int*)d_in[1];
    const float* Wih  = (const float*)d_in[2];
    const float* Whh  = (const float*)d_in[3];
    const float* bih  = (const float*)d_in[4];
    const float* bhh  = (const float*)d_in[5];
    float* out = (float*)d_out;

    // workspace layout (4-byte words)
    float* wtp       = (float*)d_ws;                 // 131072 f32
    float* b4        = wtp + 131072;                 // 512
    float* qe        = b4 + 512;                     // 128
    int*   counts    = (int*)(qe + 128);             // 32768
    int*   offs      = counts + NSEG;                // 32768
    int*   cursor    = offs + NSEG;                  // 32768
    int*   chunk_lst = cursor + NSEG;                // 32768
    int*   activeLst = chunk_lst + NCHUNK;           // 32768
    int*   nActive   = activeLst + NSEG;             // 1

    pack_weights_kernel<<<256, 128, 0, stream>>>(Wih, Whh, bih, bhh, wtp, b4);
    zero_kernel<<<64, 256, 0, stream>>>(counts, NSEG);
    zero_kernel<<<1, 64, 0, stream>>>(nActive, 1);
    seg_count_kernel<<<NCHUNK / 256, 256, 0, stream>>>(batch, counts);
    scan_kernel<<<1, 1024, 0, stream>>>(counts, offs, cursor, activeLst, nActive);
    fill_kernel<<<NCHUNK / 256, 256, 0, stream>>>(batch, cursor, chunk_lst);
    empty_traj_kernel<<<1, 128, 0, stream>>>(wtp, b4, qe);
    bcast_empty_kernel<<<512, 256, 0, stream>>>(counts, qe, out);
    main_seg_kernel<<<MGRID, MTHREADS, 0, stream>>>(
        x, wtp, b4, counts, offs, chunk_lst, activeLst, nActive, out);
}

// Round 7
// 615.966 us; speedup vs baseline: 1.1506x; 1.1506x over previous
//
#include <hip/hip_runtime.h>
#include <hip/hip_bf16.h>
#include <hip/hip_fp16.h>
#include <cstdint>

// N=1048576 nodes, B=32768 graphs, F=128, STEPS=6.
// The reference's setup overflows int32 (JAX no-x64): batch[i] =
// wrap_i32(i*32768) // 2^20 in {-2048..2047}. JAX segment ops DROP ids
// outside [0,B); gathers wrap but those contributions land in dropped ids.
// => active segments are 0..2047, each with exactly 8 chunks of 32 nodes;
// all other segments are empty -> [q_empty, 0]. Segment->chunk lists are
// built from d_in[1] on device (drop out-of-range), so we stay correct for
// both the overflowed and the clean (i//32) batch.
//
// Weight residency lessons (R5/R6): 512 KB f32 == the whole per-CU register
// file; persistent VGPR copies spill (WRITE_SIZE 2->122 MB), and plain
// "streamed" loads are loop-invariant so LICM hoists them right back into a
// spilled array (R6 counters identical to R5). This version streams fp16
// weights with an asm-laundered base index (un-hoistable) and a 2-group
// software pipeline issued a full phase-cycle early.

#define NSTEPS   6
#define NSEG     32768
#define NCHUNK   32768      // 32-node chunks
#define MAXC     8          // exactly 8 chunks/active segment (structural)
#define XSTR     132        // padded LDS row stride (floats)
#define MTHREADS 1024
#define MGRID    256        // persistent: 1 WG/CU, each loops ~8 segments
#define ESHIFT   20.0f      // constant softmax shift (ratio-invariant)

__device__ __forceinline__ float sigmoidf_(float v) {
    return 1.0f / (1.0f + __expf(-v));
}

// ---------------- weight packing (merged W_ih + W_hh, h == q_star[:128]) ----
// wtp: f32 [k][f][4 gates] (used by empty_traj); b4: bias packed.
__global__ void pack_weights_kernel(const float* __restrict__ Wih,
                                    const float* __restrict__ Whh,
                                    const float* __restrict__ bih,
                                    const float* __restrict__ bhh,
                                    float* __restrict__ wtp,
                                    float* __restrict__ b4) {
    const int k = blockIdx.x;    // 0..255
    const int f = threadIdx.x;   // 0..127
    float w[4];
    #pragma unroll
    for (int j = 0; j < 4; ++j) {
        const int row = j * 128 + f;
        float v = Wih[row * 256 + k];
        if (k < 128) v += Whh[row * 128 + k];
        w[j] = v;
    }
    float4 wv; wv.x = w[0]; wv.y = w[1]; wv.z = w[2]; wv.w = w[3];
    reinterpret_cast<float4*>(wtp)[k * 128 + f] = wv;
    if (k == 0) {
        float4 bv;
        bv.x = bih[0 * 128 + f] + bhh[0 * 128 + f];
        bv.y = bih[1 * 128 + f] + bhh[1 * 128 + f];
        bv.z = bih[2 * 128 + f] + bhh[2 * 128 + f];
        bv.w = bih[3 * 128 + f] + bhh[3 * 128 + f];
        reinterpret_cast<float4*>(b4)[f] = bv;
    }
}

// f16 pack: wph[p][f] (p = kpair 0..127) = 8 halves
// {i(2p),i(2p+1), f(2p),f(2p+1), g(2p),g(2p+1), o(2p),o(2p+1)} in one uint4.
__global__ void pack_f16_kernel(const float* __restrict__ wtp,
                                uint4* __restrict__ wph) {
    const int p = blockIdx.x;    // 0..127
    const int f = threadIdx.x;   // 0..127
    const float4 w0 = reinterpret_cast<const float4*>(wtp)[(2 * p) * 128 + f];
    const float4 w1 = reinterpret_cast<const float4*>(wtp)[(2 * p + 1) * 128 + f];
    __half2 h[4];
    h[0] = __floats2half2_rn(w0.x, w1.x);
    h[1] = __floats2half2_rn(w0.y, w1.y);
    h[2] = __floats2half2_rn(w0.z, w1.z);
    h[3] = __floats2half2_rn(w0.w, w1.w);
    wph[p * 128 + f] = *reinterpret_cast<uint4*>(h);
}

// ---------------- segment building ----------------
__global__ void zero_kernel(int* __restrict__ p, int n) {
    for (int i = blockIdx.x * blockDim.x + threadIdx.x; i < n;
         i += gridDim.x * blockDim.x) p[i] = 0;
}

__global__ void seg_count_kernel(const int* __restrict__ batch,
                                 int* __restrict__ counts) {
    const int c = blockIdx.x * blockDim.x + threadIdx.x;
    if (c < NCHUNK) {
        const int v = batch[c * 32];      // constant within a 32-node chunk
        if (v >= 0 && v < NSEG)           // JAX segment ops DROP out-of-range
            atomicAdd(&counts[v], 1);
    }
}

__global__ __launch_bounds__(1024)
void scan_kernel(const int* __restrict__ counts,
                 int* __restrict__ offs, int* __restrict__ cursor,
                 int* __restrict__ activeList, int* __restrict__ nActive) {
    __shared__ int sc[1024];
    const int t = threadIdx.x;
    const int base = t * 32;
    int local[32];
    int sum = 0;
    #pragma unroll
    for (int j = 0; j < 32; ++j) { local[j] = counts[base + j]; sum += local[j]; }
    sc[t] = sum;
    __syncthreads();
    for (int d = 1; d < 1024; d <<= 1) {
        const int v = (t >= d) ? sc[t - d] : 0;
        __syncthreads();
        sc[t] += v;
        __syncthreads();
    }
    int run = sc[t] - sum;   // exclusive prefix
    for (int j = 0; j < 32; ++j) {
        const int s = base + j;
        offs[s] = run;
        cursor[s] = run;
        if (local[j] > 0) {
            const int idx = atomicAdd(nActive, 1);
            activeList[idx] = s;
        }
        run += local[j];
    }
}

__global__ void fill_kernel(const int* __restrict__ batch,
                            int* __restrict__ cursor,
                            int* __restrict__ chunk_list) {
    const int c = blockIdx.x * blockDim.x + threadIdx.x;
    if (c < NCHUNK) {
        const int v = batch[c * 32];
        if (v >= 0 && v < NSEG) {
            const int pos = atomicAdd(&cursor[v], 1);
            chunk_list[pos] = c;
        }
    }
}

// ---------------- shared trajectory for empty graphs (r == 0) --------------
__global__ __launch_bounds__(128)
void empty_traj_kernel(const float* __restrict__ wtp,
                       const float* __restrict__ b4,
                       float* __restrict__ qe) {
    __shared__ float q_s[128];
    const int f = threadIdx.x;
    const float4 bb = reinterpret_cast<const float4*>(b4)[f];
    q_s[f] = 0.0f;
    float c = 0.0f;
    __syncthreads();
    for (int step = 0; step < NSTEPS; ++step) {
        float a0 = 0.f, a1 = 0.f, a2 = 0.f, a3 = 0.f;
        for (int k = 0; k < 128; ++k) {        // r part is zero: only k<128
            const float4 w = reinterpret_cast<const float4*>(wtp)[k * 128 + f];
            const float qv = q_s[k];
            a0 = fmaf(w.x, qv, a0); a1 = fmaf(w.y, qv, a1);
            a2 = fmaf(w.z, qv, a2); a3 = fmaf(w.w, qv, a3);
        }
        __syncthreads();
        c = sigmoidf_(a1 + bb.y) * c + sigmoidf_(a0 + bb.x) * tanhf(a2 + bb.z);
        q_s[f] = sigmoidf_(a3 + bb.w) * tanhf(c);
        __syncthreads();
    }
    qe[f] = q_s[f];
}

__global__ void bcast_empty_kernel(const int* __restrict__ counts,
                                   const float* __restrict__ qe,
                                   float* __restrict__ out) {
    const int lane = threadIdx.x & 63;
    const int wave0 = (blockIdx.x * blockDim.x + threadIdx.x) >> 6;
    const int nwave = (gridDim.x * blockDim.x) >> 6;
    float4 v = make_float4(0.f, 0.f, 0.f, 0.f);
    if (lane < 32) v = reinterpret_cast<const float4*>(qe)[lane];
    for (int s = wave0; s < NSEG; s += nwave) {
        if (counts[s] != 0) continue;
        reinterpret_cast<float4*>(out)[(size_t)s * 64 + lane] = v;
    }
}

// ---------------- main: persistent WGs, pipelined f16 weight stream --------
// 1024 threads = 16 waves. Thread (f = t>>3, ko = t&7) owns gate column f,
// kpairs {mp*16 + ko*2, +1 : mp 0..7}. Weights stream from L2 as packed f16
// (16 loads x 16B per step), 2 groups in flight, first 2 groups issued at
// the END of the previous gate phase (hidden under e/r phases + barriers).
__global__ __launch_bounds__(MTHREADS)
__attribute__((amdgpu_waves_per_eu(4, 4)))
void main_seg_kernel(const float* __restrict__ x,
                     const uint4* __restrict__ wph,
                     const float* __restrict__ b4,
                     const int* __restrict__ counts,
                     const int* __restrict__ offs,
                     const int* __restrict__ chunk_list,
                     const int* __restrict__ activeList,
                     const int* __restrict__ nActive,
                     float* __restrict__ out) {
    __shared__ __align__(16) float x_s[MAXC * 32 * XSTR];   // 135168 B
    __shared__ __align__(16) float q_s[2][256];             // dbuf [q | r]
    __shared__ __align__(16) float e_s[256];                // exp(e - 20)
    __shared__ float rpart_s[1024];                         // 8 x 128
    __shared__ float dsum_s[16];
    __shared__ int   clist_s[MAXC];
    __shared__ int   cnt_s;

    const int t  = threadIdx.x;
    const int ko = t & 7;                 // k-eighth
    const int f  = t >> 3;                // 0..127
    const float4 bb = reinterpret_cast<const float4*>(b4)[f];
    const int nAct = *nActive;

    // initial prefetch of groups 0,1 (kpairs laundered through asm => no LICM)
    uint4 p0, p1, p2, p3;
    {
        int pb = ko * 2;
        asm volatile("" : "+v"(pb));
        p0 = wph[(pb + 0) * 128 + f];
        p1 = wph[(pb + 1) * 128 + f];
        p2 = wph[(pb + 16) * 128 + f];
        p3 = wph[(pb + 17) * 128 + f];
    }

    for (int w = blockIdx.x; w < nAct; w += gridDim.x) {
        const int s = activeList[w];
        if (t == 0) {
            int cnt = counts[s];
            if (cnt > MAXC) cnt = MAXC;    // structurally impossible; clamp
            const int off = offs[s];
            for (int j = 0; j < cnt; ++j) clist_s[j] = chunk_list[off + j];
            for (int a = 1; a < cnt; ++a) {          // sort: deterministic
                const int key = clist_s[a];
                int b = a - 1;
                while (b >= 0 && clist_s[b] > key) { clist_s[b+1] = clist_s[b]; --b; }
                clist_s[b+1] = key;
            }
            cnt_s = cnt;
        }
        if (t < 256) q_s[0][t] = 0.0f;
        __syncthreads();
        const int cnt = cnt_s;
        const int nv  = cnt * 32;          // valid nodes (256 in practice)

        // ---- stage chunks into LDS (f32, padded rows), coalesced float4 ----
        for (int p = t; p < cnt * 1024; p += MTHREADS) {
            const int j   = p >> 10;
            const int q4  = p & 1023;
            const int row = q4 >> 5;
            const int c4  = q4 & 31;
            const float4 v = reinterpret_cast<const float4*>(x)
                                [(size_t)clist_s[j] * 1024 + q4];
            *reinterpret_cast<float4*>(&x_s[(j * 32 + row) * XSTR + c4 * 4]) = v;
        }
        float c_reg = 0.0f;
        __syncthreads();

        for (int step = 0; step < NSTEPS; ++step) {
            const float* qin  = q_s[step & 1];
            float*       qout = q_s[(step & 1) ^ 1];

            // ---- gates: 8-way k-split GEMV, pipelined f16 weight stream ----
            float a0 = 0.f, a1 = 0.f, a2 = 0.f, a3 = 0.f;
            int pb = ko * 2;
            asm volatile("" : "+v"(pb));   // fresh opaque base: loads stay in-loop
            uint4 c0 = p0, c1 = p1, n0 = p2, n1 = p3;
            #pragma unroll
            for (int mp = 0; mp < 8; ++mp) {
                const float4 qv =
                    *reinterpret_cast<const float4*>(&qin[mp * 32 + ko * 4]);
                const uint4 wa = c0, wb = c1;
                c0 = n0; c1 = n1;
                if (mp < 6) {
                    n0 = wph[(pb + (mp + 2) * 16 + 0) * 128 + f];
                    n1 = wph[(pb + (mp + 2) * 16 + 1) * 128 + f];
                }
                // kpair A: k=2P,2P+1 <-> qv.x,qv.y
                const __half2* ha = reinterpret_cast<const __half2*>(&wa);
                const float2 wi0 = __half22float2(ha[0]);
                const float2 wf0 = __half22float2(ha[1]);
                const float2 wg0 = __half22float2(ha[2]);
                const float2 wo0 = __half22float2(ha[3]);
                a0 = fmaf(wi0.x, qv.x, a0); a0 = fmaf(wi0.y, qv.y, a0);
                a1 = fmaf(wf0.x, qv.x, a1); a1 = fmaf(wf0.y, qv.y, a1);
                a2 = fmaf(wg0.x, qv.x, a2); a2 = fmaf(wg0.y, qv.y, a2);
                a3 = fmaf(wo0.x, qv.x, a3); a3 = fmaf(wo0.y, qv.y, a3);
                // kpair B: k=2P+2,2P+3 <-> qv.z,qv.w
                const __half2* hb = reinterpret_cast<const __half2*>(&wb);
                const float2 wi1 = __half22float2(hb[0]);
                const float2 wf1 = __half22float2(hb[1]);
                const float2 wg1 = __half22float2(hb[2]);
                const float2 wo1 = __half22float2(hb[3]);
                a0 = fmaf(wi1.x, qv.z, a0); a0 = fmaf(wi1.y, qv.w, a0);
                a1 = fmaf(wf1.x, qv.z, a1); a1 = fmaf(wf1.y, qv.w, a1);
                a2 = fmaf(wg1.x, qv.z, a2); a2 = fmaf(wg1.y, qv.w, a2);
                a3 = fmaf(wo1.x, qv.z, a3); a3 = fmaf(wo1.y, qv.w, a3);
            }
            // prefetch next gate phase's groups 0,1 (flies under e/r phases)
            {
                int pb2 = ko * 2;
                asm volatile("" : "+v"(pb2));
                p0 = wph[(pb2 + 0) * 128 + f];
                p1 = wph[(pb2 + 1) * 128 + f];
                p2 = wph[(pb2 + 16) * 128 + f];
                p3 = wph[(pb2 + 17) * 128 + f];
            }

            a0 += __shfl_xor(a0, 1); a0 += __shfl_xor(a0, 2); a0 += __shfl_xor(a0, 4);
            a1 += __shfl_xor(a1, 1); a1 += __shfl_xor(a1, 2); a1 += __shfl_xor(a1, 4);
            a2 += __shfl_xor(a2, 1); a2 += __shfl_xor(a2, 2); a2 += __shfl_xor(a2, 4);
            a3 += __shfl_xor(a3, 1); a3 += __shfl_xor(a3, 2); a3 += __shfl_xor(a3, 4);
            if (ko == 0) {                 // 128 owner lanes: LSTM pointwise
                const float gi = a0 + bb.x, gf = a1 + bb.y;
                const float gg = a2 + bb.z, go = a3 + bb.w;
                c_reg = sigmoidf_(gf) * c_reg + sigmoidf_(gi) * tanhf(gg);
                qout[f] = sigmoidf_(go) * tanhf(c_reg);   // no WAR: other buffer
            }
            __syncthreads();               // B2: new q visible

            // ---- attention: 4 lanes per node; p = exp(x_n.q - 20) ----
            {
                const int n  = t >> 2;     // 0..255
                const int kh = t & 3;
                const float* xr = &x_s[n * XSTR + kh * 32];
                const float* qr = &qout[kh * 32];
                float part = 0.f;
                #pragma unroll
                for (int kk = 0; kk < 32; kk += 4) {
                    const float4 xv = *reinterpret_cast<const float4*>(xr + kk);
                    const float4 qv = *reinterpret_cast<const float4*>(qr + kk);
                    part = fmaf(xv.x, qv.x, part);
                    part = fmaf(xv.y, qv.y, part);
                    part = fmaf(xv.z, qv.z, part);
                    part = fmaf(xv.w, qv.w, part);
                }
                part += __shfl_xor(part, 1);
                part += __shfl_xor(part, 2);             // full 128-dot
                const float p = (n < nv) ? __expf(part - ESHIFT) : 0.f;
                if (kh == 0) e_s[n] = p;
                float ws = (kh == 0) ? p : 0.f;          // wave denom partial
                ws += __shfl_xor(ws, 4);  ws += __shfl_xor(ws, 8);
                ws += __shfl_xor(ws, 16); ws += __shfl_xor(ws, 32);
                if ((t & 63) == 0) dsum_s[t >> 6] = ws;
            }
            __syncthreads();               // B3: e_s + dsum visible

            // ---- readout partials: wave nh owns 32-node chunk ----
            {
                const int nh  = t >> 7;    // 0..7
                const int fr  = t & 127;
                const int nlo = nh * 32;
                float part = 0.f;
                if (nlo < nv) {
                    const float* xc = &x_s[nlo * XSTR + fr];
                    const float* ec = &e_s[nlo];
                    #pragma unroll 8
                    for (int j = 0; j < 32; ++j)
                        part = fmaf(ec[j], xc[j * XSTR], part);
                }
                rpart_s[nh * 128 + fr] = part;
            }
            __syncthreads();               // B4: rpart visible
            if (t < 128) {
                float den = 0.f;
                #pragma unroll
                for (int j = 0; j < 16; ++j) den += dsum_s[j];
                const float rsum = rpart_s[t]       + rpart_s[128 + t]
                                 + rpart_s[256 + t] + rpart_s[384 + t]
                                 + rpart_s[512 + t] + rpart_s[640 + t]
                                 + rpart_s[768 + t] + rpart_s[896 + t];
                qout[128 + t] = rsum / den;
            }
            __syncthreads();               // B5: r visible for next gate phase
        }
        // after 6 steps the final q_star sits in q_s[0]
        if (t < 64)
            reinterpret_cast<float4*>(out + (size_t)s * 256)[t] =
                reinterpret_cast<const float4*>(&q_s[0][0])[t];
        __syncthreads();                   // before LDS reuse for next segment
    }
}

extern "C" void kernel_launch(void* const* d_in, const int* in_sizes, int n_in,
                              void* d_out, int out_size, void* d_ws, size_t ws_size,
                              hipStream_t stream) {
    (void)in_sizes; (void)n_in; (void)out_size; (void)ws_size;
    const float* x    = (const float*)d_in[0];
    const int*   batch = (const int*)d_in[1];
    const float* Wih  = (const float*)d_in[2];
    const float* Whh  = (const float*)d_in[3];
    const float* bih  = (const float*)d_in[4];
    const float* bhh  = (const float*)d_in[5];
    float* out = (float*)d_out;

    // workspace layout (4-byte words)
    float* wtp       = (float*)d_ws;                 // 131072 f32 (f32 weights)
    float* b4        = wtp + 131072;                 // 512
    float* qe        = b4 + 512;                     // 128
    uint4* wph       = (uint4*)(qe + 128);           // 128*128 uint4 = 256 KB
    int*   counts    = (int*)(wph + 128 * 128);      // 32768
    int*   offs      = counts + NSEG;                // 32768
    int*   cursor    = offs + NSEG;                  // 32768
    int*   chunk_lst = cursor + NSEG;                // 32768
    int*   activeLst = chunk_lst + NCHUNK;           // 32768
    int*   nActive   = activeLst + NSEG;             // 1

    pack_weights_kernel<<<256, 128, 0, stream>>>(Wih, Whh, bih, bhh, wtp, b4);
    pack_f16_kernel<<<128, 128, 0, stream>>>(wtp, wph);
    zero_kernel<<<64, 256, 0, stream>>>(counts, NSEG);
    zero_kernel<<<1, 64, 0, stream>>>(nActive, 1);
    seg_count_kernel<<<NCHUNK / 256, 256, 0, stream>>>(batch, counts);
    scan_kernel<<<1, 1024, 0, stream>>>(counts, offs, cursor, activeLst, nActive);
    fill_kernel<<<NCHUNK / 256, 256, 0, stream>>>(batch, cursor, chunk_lst);
    empty_traj_kernel<<<1, 128, 0, stream>>>(wtp, b4, qe);
    bcast_empty_kernel<<<512, 256, 0, stream>>>(counts, qe, out);
    main_seg_kernel<<<MGRID, MTHREADS, 0, stream>>>(
        x, wph, b4, counts, offs, chunk_lst, activeLst, nActive, out);
}